// Round 5
// baseline (23.596 us; speedup 1.0000x reference)
//
#include <hip/hip_runtime.h>
#include <math.h>

// y[k] = Re( phase * z_c^k ),  z_c = z * tanh(|z|)/|z|
//      = r^k * (ph_re*cos(k*theta) - ph_im*sin(k*theta)),
//   r = tanh(|z|), theta = atan2(z_im, z_re).
// r^k underflows f32 by k ~ -90/ln(r) (~330 for |z|=1) -> all but the first
// few hundred outputs are exact zeros in the reference cumprod.
//
// Structure: each block owns a contiguous 2048-float4 (32 KB) chunk.
// Zero-tail blocks (all but ~1) run a minimal prologue {2 loads, tanh, log,
// cmp} then a pure 8x dwordx4 store loop. Only the head block computes
// transcendentals per element (and is the only one touching ph/atan2).

typedef float f32x4 __attribute__((ext_vector_type(4)));

#define F4_PER_BLOCK 2048LL   // 8 per thread * 256 threads

__global__ void __launch_bounds__(256)
osc_kernel(const float* __restrict__ z_re_p, const float* __restrict__ z_im_p,
           const float* __restrict__ ph_re_p, const float* __restrict__ ph_im_p,
           float* __restrict__ out, long long n4, long long N) {
    const float zr = *z_re_p;
    const float zi = *z_im_p;

    const float mag = sqrtf(zr * zr + zi * zi);
    const float r   = tanhf(mag);            // constrained magnitude, < 1
    const float lr  = logf(r);               // < 0
    // k >= kcut  =>  k*lr < -90  =>  r^k < ~8e-40  => reference f32 value is 0.
    const float kcutf = (lr < 0.0f) ? (-90.0f / lr) : 3.4e38f;

    const long long blockBase = (long long)blockIdx.x * F4_PER_BLOCK; // f4 units
    const int tid = threadIdx.x;
    f32x4* __restrict__ out4 = reinterpret_cast<f32x4*>(out);

    const bool full    = (blockBase + F4_PER_BLOCK) <= n4;
    // e = k*lr decreases with k: if the block's first element underflows,
    // the whole 32 KB chunk is zero.
    const bool allzero = ((float)(blockBase * 4) >= kcutf);

    if (full && allzero) {
        const f32x4 z4 = {0.f, 0.f, 0.f, 0.f};
        f32x4* p = out4 + blockBase + tid;
#pragma unroll
        for (int u = 0; u < 8; ++u)
            p[(long long)u * 256] = z4;
    } else {
        // compute path: needs angle and phase too
        const float pr    = *ph_re_p;
        const float pi    = *ph_im_p;
        const float theta = atan2f(zi, zr);
#pragma unroll
        for (int u = 0; u < 8; ++u) {
            const long long i4 = blockBase + tid + (long long)u * 256;
            if (i4 >= n4) break;
            const long long k0 = i4 * 4;
            f32x4 v;
#pragma unroll
            for (int j = 0; j < 4; ++j) {
                const float k = (float)(k0 + j);
                const float e = k * lr;
                if (e < -90.0f) {
                    v[j] = 0.0f;
                } else {
                    const float rk = expf(e);
                    float s, c;
                    sincosf(k * theta, &s, &c);
                    v[j] = rk * (pr * c - pi * s);
                }
            }
            out4[i4] = v;
        }
        // scalar tail if N not divisible by 4 (not the case for N=2^25)
        if (blockIdx.x == 0 && tid == 0) {
            for (long long idx = n4 * 4; idx < N; ++idx) {
                const float k = (float)idx;
                const float e = k * lr;
                if (e < -90.0f) {
                    out[idx] = 0.0f;
                } else {
                    const float rk = expf(e);
                    float s, c;
                    sincosf(k * theta, &s, &c);
                    out[idx] = rk * (pr * c - pi * s);
                }
            }
        }
    }
}

extern "C" void kernel_launch(void* const* d_in, const int* in_sizes, int n_in,
                              void* d_out, int out_size, void* d_ws, size_t ws_size,
                              hipStream_t stream) {
    const float* z_re = (const float*)d_in[0];
    const float* z_im = (const float*)d_in[1];
    const float* ph_re = (const float*)d_in[2];
    const float* ph_im = (const float*)d_in[3];
    float* out = (float*)d_out;

    const long long N  = (long long)out_size;
    const long long n4 = N / 4;

    long long nb = (n4 + F4_PER_BLOCK - 1) / F4_PER_BLOCK;
    if (nb < 1) nb = 1;
    osc_kernel<<<(int)nb, 256, 0, stream>>>(z_re, z_im, ph_re, ph_im, out, n4, N);
}